// Round 1
// baseline (957.611 us; speedup 1.0000x reference)
//
#include <hip/hip_runtime.h>
#include <hip/hip_bf16.h>
#include <cstdint>

// Problem constants (from reference): B=256, C=2048, H*W=196, E=16, A=3000
#define BN   256
#define CN   2048
#define HWN  196
#define EN   16
#define AN   3000

// GEMM tile params
#define TS   32            // samples per tile
#define TA   64            // answers per tile
#define KC   32            // K-chunk
#define LDST 36            // LDS row stride in floats (KC+4: breaks bank aliasing, keeps 16B align)

// ---------------------------------------------------------------------------
// Kernel 1: masked weighted average pool.
// One wave (64 lanes) per (b,c) row of 196 floats = 49 float4.
// Lanes 0..48 each load one float4 of features and mask, accumulate
// num = sum((m+1e-10)*f), den = sum(m+1e-10), then wave-reduce.
// ---------------------------------------------------------------------------
__global__ __launch_bounds__(256) void pool_kernel(const float* __restrict__ mask,
                                                   const float* __restrict__ feat,
                                                   float* __restrict__ attended) {
    int wave = blockIdx.x * 4 + (threadIdx.x >> 6);   // global wave id = b*CN + c
    int lane = threadIdx.x & 63;
    int b = wave / CN;
    int c = wave % CN;

    const float4* frow = (const float4*)(feat + ((size_t)b * CN + c) * HWN);
    const float4* mrow = (const float4*)(mask + (size_t)b * HWN);

    float num = 0.f, den = 0.f;
    if (lane < HWN / 4) {            // 49 active lanes
        float4 f = frow[lane];
        float4 m = mrow[lane];
        float mx = m.x + 1e-10f, my = m.y + 1e-10f;
        float mz = m.z + 1e-10f, mw = m.w + 1e-10f;
        num = mx * f.x + my * f.y + mz * f.z + mw * f.w;
        den = mx + my + mz + mw;
    }
    // butterfly reduce across 64 lanes
    #pragma unroll
    for (int off = 32; off; off >>= 1) {
        num += __shfl_xor(num, off, 64);
        den += __shfl_xor(den, off, 64);
    }
    if (lane == 0) attended[(size_t)b * CN + c] = num / den;
}

// ---------------------------------------------------------------------------
// Kernel 2: group samples by expert. Single block, 256 threads.
// counts[e] = #samples with inst==e; lists[e*BN + i] = sample ids.
// ---------------------------------------------------------------------------
__global__ void group_kernel(const int* __restrict__ inst,
                             int* __restrict__ counts,
                             int* __restrict__ lists) {
    __shared__ int cnt[EN];
    int t = threadIdx.x;
    if (t < EN) cnt[t] = 0;
    __syncthreads();
    if (t < BN) {
        int e = inst[t];
        int pos = atomicAdd(&cnt[e], 1);
        lists[e * BN + pos] = t;
    }
    __syncthreads();
    if (t < EN) counts[t] = cnt[t];
}

// ---------------------------------------------------------------------------
// Kernel 3: grouped expert GEMM.
// Grid: (ceil(AN/TA), EN). Block = 128 threads.
// Block computes out[s, a0:a0+64] for up to 32 samples of expert e.
// Per-thread 4x4 register tile; samples strided by 8, answers by 16
// (conflict-free ds_read_b128 with LDST=36 row stride).
// W[e] is streamed from HBM exactly once per expert (for n_e <= 32).
// ---------------------------------------------------------------------------
__global__ __launch_bounds__(128) void gemm_kernel(const float* __restrict__ attended,
                                                   const float* __restrict__ W,
                                                   const float* __restrict__ bias,
                                                   const int* __restrict__ counts,
                                                   const int* __restrict__ lists,
                                                   float* __restrict__ out) {
    int e  = blockIdx.y;
    int a0 = blockIdx.x * TA;
    int n  = counts[e];
    if (n == 0) return;

    __shared__ float At[TS * LDST];
    __shared__ float Wt[TA * LDST];
    __shared__ int   sid[TS];

    int t  = threadIdx.x;
    int ts = t & 7;        // sample group (8 groups of 4, stride 8)
    int ta = t >> 3;       // answer group (16 groups of 4, stride 16)
    const int* lst = lists + e * BN;

    for (int s0 = 0; s0 < n; s0 += TS) {
        if (t < TS) sid[t] = (s0 + t < n) ? lst[s0 + t] : -1;

        float acc[4][4];
        #pragma unroll
        for (int i = 0; i < 4; i++)
            #pragma unroll
            for (int j = 0; j < 4; j++) acc[i][j] = 0.f;

        __syncthreads();   // sid visible

        for (int k0 = 0; k0 < CN; k0 += KC) {
            // stage At: 32 rows x 8 float4 = 256 f4, 2 per thread
            #pragma unroll
            for (int r = 0; r < 2; r++) {
                int q = t + r * 128;
                int row = q >> 3, pos = q & 7;
                int s = sid[row];
                float4 v = make_float4(0.f, 0.f, 0.f, 0.f);
                if (s >= 0) v = *(const float4*)(attended + (size_t)s * CN + k0 + pos * 4);
                *(float4*)(&At[row * LDST + pos * 4]) = v;
            }
            // stage Wt: 64 rows x 8 float4 = 512 f4, 4 per thread (coalesced 128B/row)
            #pragma unroll
            for (int r = 0; r < 4; r++) {
                int q = t + r * 128;
                int row = q >> 3, pos = q & 7;
                int a = a0 + row;
                if (a < AN) {
                    float4 v = *(const float4*)(W + ((size_t)e * AN + a) * CN + k0 + pos * 4);
                    *(float4*)(&Wt[row * LDST + pos * 4]) = v;
                }
            }
            __syncthreads();

            // compute: 8 chunks of 4 k-values; 8 b128 LDS reads + 64 FMAs per chunk
            #pragma unroll
            for (int kc = 0; kc < KC / 4; kc++) {
                float4 av[4], wv[4];
                #pragma unroll
                for (int i = 0; i < 4; i++)
                    av[i] = *(const float4*)(&At[(ts + 8 * i) * LDST + kc * 4]);
                #pragma unroll
                for (int j = 0; j < 4; j++)
                    wv[j] = *(const float4*)(&Wt[(ta + 16 * j) * LDST + kc * 4]);
                #pragma unroll
                for (int i = 0; i < 4; i++)
                    #pragma unroll
                    for (int j = 0; j < 4; j++) {
                        acc[i][j] += av[i].x * wv[j].x;
                        acc[i][j] += av[i].y * wv[j].y;
                        acc[i][j] += av[i].z * wv[j].z;
                        acc[i][j] += av[i].w * wv[j].w;
                    }
            }
            __syncthreads();
        }

        // epilogue: add bias, scatter to out rows
        #pragma unroll
        for (int j = 0; j < 4; j++) {
            int a = a0 + ta + 16 * j;
            if (a < AN) {
                float bj = bias[e * AN + a];
                #pragma unroll
                for (int i = 0; i < 4; i++) {
                    int s = sid[ts + 8 * i];
                    if (s >= 0) out[(size_t)s * AN + a] = acc[i][j] + bj;
                }
            }
        }
        __syncthreads();   // before next tile rewrites sid/At/Wt
    }
}

// ---------------------------------------------------------------------------
extern "C" void kernel_launch(void* const* d_in, const int* in_sizes, int n_in,
                              void* d_out, int out_size, void* d_ws, size_t ws_size,
                              hipStream_t stream) {
    const float* mask = (const float*)d_in[0];
    const float* feat = (const float*)d_in[1];
    const float* W    = (const float*)d_in[2];
    const float* bias = (const float*)d_in[3];
    const int*   inst = (const int*)d_in[4];
    float* out = (float*)d_out;

    char* ws = (char*)d_ws;
    float* attended = (float*)ws;                                 // 256*2048*4 = 2 MB
    int*   counts   = (int*)(ws + (size_t)BN * CN * sizeof(float));
    int*   lists    = counts + EN;                                // 16*256 ints

    // 1) masked pool: one wave per (b,c); 4 waves per block
    pool_kernel<<<BN * CN / 4, 256, 0, stream>>>(mask, feat, attended);

    // 2) group samples by expert
    group_kernel<<<1, 256, 0, stream>>>(inst, counts, lists);

    // 3) grouped expert GEMM
    dim3 grid((AN + TA - 1) / TA, EN);
    gemm_kernel<<<grid, 128, 0, stream>>>(attended, W, bias, counts, lists, out);
}

// Round 2
// 870.620 us; speedup vs baseline: 1.0999x; 1.0999x over previous
//
#include <hip/hip_runtime.h>
#include <cstdint>

// Problem constants: B=256, C=2048, H*W=196, E=16, A=3000
#define BN   256
#define CN   2048
#define HWN  196
#define EN   16
#define AN   3000

// GEMM tile params
#define TS   32            // samples per tile
#define TA   64            // answers per tile
#define KC   32            // K-chunk staged per iteration
#define LDST 36            // LDS row stride (KC+4): conflict-free b128 (measured 0 conflicts R1)
#define KSPLIT 4           // K-dimension split for occupancy (grid 752 -> 3008 blocks)
#define KPART (CN / KSPLIT)

#define RPW  8             // pool: channel rows per wave

// ---------------------------------------------------------------------------
// Kernel 0: per-sample mask denominator. One wave per b; rden[b] = 1/sum(m+eps).
// ---------------------------------------------------------------------------
__global__ __launch_bounds__(256) void den_kernel(const float* __restrict__ mask,
                                                  float* __restrict__ rden) {
    int wave = blockIdx.x * 4 + (threadIdx.x >> 6);   // = b
    int lane = threadIdx.x & 63;
    float den = 0.f;
    if (lane < HWN / 4) {
        float4 m = ((const float4*)(mask + (size_t)wave * HWN))[lane];
        den = (m.x + 1e-10f) + (m.y + 1e-10f) + (m.z + 1e-10f) + (m.w + 1e-10f);
    }
    #pragma unroll
    for (int off = 32; off; off >>= 1) den += __shfl_xor(den, off, 64);
    if (lane == 0) rden[wave] = 1.0f / den;
}

// ---------------------------------------------------------------------------
// Kernel 1: masked weighted pool. One wave handles 8 consecutive channel rows
// of one sample: mask f4 held in registers (reused 8x), 8 independent
// butterflies interleaved (latency overlap), denominator precomputed.
// ---------------------------------------------------------------------------
__global__ __launch_bounds__(256) void pool_kernel(const float* __restrict__ mask,
                                                   const float* __restrict__ feat,
                                                   const float* __restrict__ rden,
                                                   float* __restrict__ attended) {
    int wave = blockIdx.x * 4 + (threadIdx.x >> 6);
    int lane = threadIdx.x & 63;
    int b  = wave >> 8;               // 2048/RPW = 256 waves per sample
    int c0 = (wave & 255) * RPW;
    bool act = lane < HWN / 4;        // 49 active lanes

    float4 m = make_float4(0.f, 0.f, 0.f, 0.f);
    if (act) {
        m = ((const float4*)(mask + (size_t)b * HWN))[lane];
        m.x += 1e-10f; m.y += 1e-10f; m.z += 1e-10f; m.w += 1e-10f;
    }
    const float4* fb = (const float4*)(feat + ((size_t)b * CN + c0) * HWN);
    float4 f[RPW];
    #pragma unroll
    for (int r = 0; r < RPW; r++)
        f[r] = act ? fb[r * (HWN / 4) + lane] : make_float4(0.f, 0.f, 0.f, 0.f);
    float num[RPW];
    #pragma unroll
    for (int r = 0; r < RPW; r++)
        num[r] = m.x * f[r].x + m.y * f[r].y + m.z * f[r].z + m.w * f[r].w;
    #pragma unroll
    for (int off = 32; off; off >>= 1)
        #pragma unroll
        for (int r = 0; r < RPW; r++) num[r] += __shfl_xor(num[r], off, 64);
    if (lane == 0) {
        float rd = rden[b];
        #pragma unroll
        for (int r = 0; r < RPW; r++)
            attended[(size_t)b * CN + c0 + r] = num[r] * rd;
    }
}

// ---------------------------------------------------------------------------
// Kernel 2: group samples by expert.
// ---------------------------------------------------------------------------
__global__ void group_kernel(const int* __restrict__ inst,
                             int* __restrict__ counts,
                             int* __restrict__ lists) {
    __shared__ int cnt[EN];
    int t = threadIdx.x;
    if (t < EN) cnt[t] = 0;
    __syncthreads();
    if (t < BN) {
        int e = inst[t];
        int pos = atomicAdd(&cnt[e], 1);
        lists[e * BN + pos] = t;
    }
    __syncthreads();
    if (t < EN) counts[t] = cnt[t];
}

// ---------------------------------------------------------------------------
// Kernel 3: out[b, :] = bias[inst[b], :]  (K-split partials atomicAdd on top)
// ---------------------------------------------------------------------------
__global__ __launch_bounds__(256) void bias_init_kernel(const float* __restrict__ bias,
                                                        const int* __restrict__ inst,
                                                        float* __restrict__ out) {
    int b = blockIdx.x;
    int e = inst[b];
    const float4* br = (const float4*)(bias + (size_t)e * AN);
    float4* orow = (float4*)(out + (size_t)b * AN);
    for (int j = threadIdx.x; j < AN / 4; j += 256) orow[j] = br[j];
}

// ---------------------------------------------------------------------------
// Kernel 4: grouped expert GEMM, K-split, register-prefetched staging.
// Grid (ceil(AN/TA), EN, KSPLIT), 128 threads. Each block: 32 samples x 64
// answers over K=512. Next chunk's global loads issue before compute so the
// ~900 cyc HBM latency hides under the ~1024 cyc FMA chunk.
// ---------------------------------------------------------------------------
__global__ __launch_bounds__(128, 4) void gemm_kernel(const float* __restrict__ attended,
                                                      const float* __restrict__ W,
                                                      const int* __restrict__ counts,
                                                      const int* __restrict__ lists,
                                                      float* __restrict__ out) {
    int e  = blockIdx.y;
    int kp = blockIdx.z;
    int a0 = blockIdx.x * TA;
    int n  = counts[e];
    if (n == 0) return;
    int kbeg = kp * KPART;
    int kend = kbeg + KPART;

    __shared__ float At[TS * LDST];
    __shared__ float Wt[TA * LDST];
    __shared__ int   sid[TS];

    int t    = threadIdx.x;
    int ts   = t & 7;        // sample group (stride 8)
    int ta   = t >> 3;       // answer group (stride 16)
    int srow = t >> 3;       // staging row base
    int spos = t & 7;        // staging f4 position
    const int* lst = lists + e * BN;

    for (int s0 = 0; s0 < n; s0 += TS) {
        if (t < TS) sid[t] = (s0 + t < n) ? lst[s0 + t] : -1;

        float acc[4][4];
        #pragma unroll
        for (int i = 0; i < 4; i++)
            #pragma unroll
            for (int j = 0; j < 4; j++) acc[i][j] = 0.f;

        __syncthreads();   // sid visible

        float4 apre[2], wpre[4];
        // prologue prefetch (chunk kbeg)
        #pragma unroll
        for (int r = 0; r < 2; r++) {
            int s = sid[srow + 16 * r];
            apre[r] = make_float4(0.f, 0.f, 0.f, 0.f);
            if (s >= 0)
                apre[r] = *(const float4*)(attended + (size_t)s * CN + kbeg + spos * 4);
        }
        #pragma unroll
        for (int r = 0; r < 4; r++) {
            int a = a0 + srow + 16 * r; if (a > AN - 1) a = AN - 1;   // clamp, result discarded
            wpre[r] = *(const float4*)(W + ((size_t)e * AN + a) * CN + kbeg + spos * 4);
        }

        for (int k0 = kbeg; k0 < kend; k0 += KC) {
            // commit prefetched chunk to LDS
            #pragma unroll
            for (int r = 0; r < 2; r++)
                *(float4*)(&At[(srow + 16 * r) * LDST + spos * 4]) = apre[r];
            #pragma unroll
            for (int r = 0; r < 4; r++)
                *(float4*)(&Wt[(srow + 16 * r) * LDST + spos * 4]) = wpre[r];
            __syncthreads();

            // prefetch next chunk (retires during compute)
            if (k0 + KC < kend) {
                int kn = k0 + KC;
                #pragma unroll
                for (int r = 0; r < 2; r++) {
                    int s = sid[srow + 16 * r];
                    apre[r] = make_float4(0.f, 0.f, 0.f, 0.f);
                    if (s >= 0)
                        apre[r] = *(const float4*)(attended + (size_t)s * CN + kn + spos * 4);
                }
                #pragma unroll
                for (int r = 0; r < 4; r++) {
                    int a = a0 + srow + 16 * r; if (a > AN - 1) a = AN - 1;
                    wpre[r] = *(const float4*)(W + ((size_t)e * AN + a) * CN + kn + spos * 4);
                }
            }

            // compute: 8 chunks x (8 conflict-free b128 reads + 64 FMA)
            #pragma unroll
            for (int kc = 0; kc < KC / 4; kc++) {
                float4 av[4], wv[4];
                #pragma unroll
                for (int i = 0; i < 4; i++)
                    av[i] = *(const float4*)(&At[(ts + 8 * i) * LDST + kc * 4]);
                #pragma unroll
                for (int j = 0; j < 4; j++)
                    wv[j] = *(const float4*)(&Wt[(ta + 16 * j) * LDST + kc * 4]);
                #pragma unroll
                for (int i = 0; i < 4; i++)
                    #pragma unroll
                    for (int j = 0; j < 4; j++) {
                        acc[i][j] += av[i].x * wv[j].x;
                        acc[i][j] += av[i].y * wv[j].y;
                        acc[i][j] += av[i].z * wv[j].z;
                        acc[i][j] += av[i].w * wv[j].w;
                    }
            }
            __syncthreads();
        }

        // epilogue: accumulate K-split partial into bias-initialized out
        #pragma unroll
        for (int j = 0; j < 4; j++) {
            int a = a0 + ta + 16 * j;
            if (a < AN) {
                #pragma unroll
                for (int i = 0; i < 4; i++) {
                    int s = sid[ts + 8 * i];
                    if (s >= 0) atomicAdd(&out[(size_t)s * AN + a], acc[i][j]);
                }
            }
        }
        __syncthreads();   // sid/LDS reused next tile
    }
}

// ---------------------------------------------------------------------------
extern "C" void kernel_launch(void* const* d_in, const int* in_sizes, int n_in,
                              void* d_out, int out_size, void* d_ws, size_t ws_size,
                              hipStream_t stream) {
    const float* mask = (const float*)d_in[0];
    const float* feat = (const float*)d_in[1];
    const float* W    = (const float*)d_in[2];
    const float* bias = (const float*)d_in[3];
    const int*   inst = (const int*)d_in[4];
    float* out = (float*)d_out;

    char* ws = (char*)d_ws;
    float* attended = (float*)ws;                                  // 2 MB
    float* rden     = (float*)(ws + (size_t)BN * CN * sizeof(float));
    int*   counts   = (int*)(rden + BN);
    int*   lists    = counts + EN;

    // 0) per-sample reciprocal denominator
    den_kernel<<<BN / 4, 256, 0, stream>>>(mask, rden);
    // 1) group samples by expert
    group_kernel<<<1, 256, 0, stream>>>(inst, counts, lists);
    // 2) masked pool (8 rows/wave)
    pool_kernel<<<BN * CN / RPW / 4, 256, 0, stream>>>(mask, feat, rden, attended);
    // 3) out = bias[inst[b]]
    bias_init_kernel<<<BN, 256, 0, stream>>>(bias, inst, out);
    // 4) grouped GEMM, K-split x4, atomic accumulate
    dim3 grid((AN + TA - 1) / TA, EN, KSPLIT);
    gemm_kernel<<<grid, 128, 0, stream>>>(attended, W, counts, lists, out);
}